// Round 11
// baseline (293.530 us; speedup 1.0000x reference)
//
#include <hip/hip_runtime.h>

// RGCNConv basis-decomposed, sort-based aggregation + 8-phase pipelined bf16 MFMA GEMM.
//   Abf = [seg_sum(bf16(x)[src] by (dst,rel)) | bf16(x)]  (bf16, [N][2304])
//   out = Abf @ WcatT^T + bias                            (f32 out)
// R11: GEMM col-fastest XCD ordering (A-panel L2 reuse); 1-seg/wave aggregate;
// fused init kernel (zero cnt ∥ xcast ∥ wcat).

#define N_NODES 20000
#define N_EDGES 640000
#define IN_DIM  256
#define OUT_DIM 800
#define NREL    8
#define NSEG    160000          // N_NODES * NREL
#define KS      2048            // NREL * IN_DIM
#define KTOT    2304            // KS + IN_DIM
#define NPAD    1024            // padded N for GEMM B (4 x 256)
#define NB      625             // NSEG / 256 scan blocks

// GEMM geometry: 128x256 tile, BK=64, 8 waves (2Mx4N, 64x64), triple-buffer LDS
#define BM 128
#define BN 256
#define BK 64
#define NKT (KTOT / BK)         // 36
#define MT  157                 // ceil(20000/128)
#define NT  4                   // 1024/256
#define NWG (MT * NT)           // 628
#define LBUF 49152              // per K-tile: A 16K | B 32K

// fused init kernel block ranges
#define XCAST_B (N_NODES * 64 / 256)   // 5000
#define INIT_NWG (NB + XCAST_B + NPAD) // 625 + 5000 + 1024 = 6649

typedef float f32x4_t __attribute__((ext_vector_type(4)));
typedef short short8_t __attribute__((ext_vector_type(8)));

__device__ __forceinline__ unsigned short f2bf(float f) {
  unsigned u = __float_as_uint(f);
  u += 0x7fffu + ((u >> 16) & 1u);
  return (unsigned short)(u >> 16);
}

__device__ __forceinline__ float bflo(unsigned w) { return __uint_as_float(w << 16); }
__device__ __forceinline__ float bfhi(unsigned w) { return __uint_as_float(w & 0xffff0000u); }

__device__ __forceinline__ void gload16(const void* g, void* l) {
  __builtin_amdgcn_global_load_lds(
      (const __attribute__((address_space(1))) void*)g,
      (__attribute__((address_space(3))) void*)l, 16, 0, 0);
}

// ---------------- fused init: zero cnt | xcast | build_wcat ----------------
__global__ void init_kernel(const float* __restrict__ x,
                            const float* __restrict__ bases,
                            const float* __restrict__ att,
                            const float* __restrict__ root,
                            int* __restrict__ cnt,
                            unsigned short* __restrict__ abf,
                            unsigned short* __restrict__ wcatT) {
  const int b = blockIdx.x;
  const int t = threadIdx.x;
  if (b < NB) {
    cnt[b * 256 + t] = 0;
  } else if (b < NB + XCAST_B) {
    const int id = (b - NB) * 256 + t;           // 20000*64
    const int row = id >> 6, lane = id & 63;
    const float4 v = ((const float4*)x)[(size_t)row * 64 + lane];
    union { unsigned short u[4]; uint2 q; } pk;
    pk.u[0] = f2bf(v.x); pk.u[1] = f2bf(v.y);
    pk.u[2] = f2bf(v.z); pk.u[3] = f2bf(v.w);
    *(uint2*)(abf + (size_t)row * KTOT + KS + lane * 4) = pk.q;
  } else {
    __shared__ float satt[64];
    const int n = b - NB - XCAST_B;              // 0..1023
    if (t < 64) satt[t] = att[t];
    __syncthreads();
    const bool valid = n < OUT_DIM;
    for (int c = t; c < KTOT / 8; c += 256) {    // 288 chunks of 8 k's
      const int k0 = c * 8;
      union { unsigned short u[8]; uint4 q; } pk;
      if (!valid) {
        pk.q = make_uint4(0u, 0u, 0u, 0u);
      } else if (k0 < KS) {
        const int r = k0 >> 8, i0 = k0 & 255;
        #pragma unroll
        for (int j = 0; j < 8; ++j) {
          float v = 0.f;
          #pragma unroll
          for (int bb = 0; bb < 8; ++bb)
            v += satt[r * 8 + bb] * bases[((size_t)bb * IN_DIM + i0 + j) * OUT_DIM + n];
          pk.u[j] = f2bf(v);
        }
      } else {
        #pragma unroll
        for (int j = 0; j < 8; ++j)
          pk.u[j] = f2bf(root[(size_t)(k0 - KS + j) * OUT_DIM + n]);
      }
      *(uint4*)(wcatT + (size_t)n * KTOT + k0) = pk.q;
    }
  }
}

// ---------------- sort pipeline ----------------

__global__ void hist_kernel(const int* __restrict__ ei, const int* __restrict__ et,
                            int* __restrict__ cnt) {
  const int e = blockIdx.x * 256 + threadIdx.x;
  const int seg = ei[N_EDGES + e] * NREL + et[e];
  atomicAdd(&cnt[seg], 1);
}

__global__ void scan_reduce_kernel(const int* __restrict__ cnt, int* __restrict__ bsum) {
  __shared__ int sm[256];
  const int t = threadIdx.x;
  sm[t] = cnt[blockIdx.x * 256 + t];
  __syncthreads();
  for (int s = 128; s > 0; s >>= 1) {
    if (t < s) sm[t] += sm[t + s];
    __syncthreads();
  }
  if (t == 0) bsum[blockIdx.x] = sm[0];
}

__global__ void scan_bsum_kernel(int* __restrict__ bsum) {
  __shared__ int sm[1024];
  const int t = threadIdx.x;
  const int v = (t < NB) ? bsum[t] : 0;
  sm[t] = v;
  __syncthreads();
  for (int s = 1; s < 1024; s <<= 1) {
    const int a = (t >= s) ? sm[t - s] : 0;
    __syncthreads();
    sm[t] += a;
    __syncthreads();
  }
  if (t < NB) bsum[t] = sm[t] - v;   // exclusive
}

__global__ void scan_final_kernel(const int* __restrict__ cnt, const int* __restrict__ bsum,
                                  int* __restrict__ off, int* __restrict__ cur) {
  __shared__ int sm[256];
  const int t = threadIdx.x;
  const int g = blockIdx.x * 256 + t;
  const int v = cnt[g];
  sm[t] = v;
  __syncthreads();
  for (int s = 1; s < 256; s <<= 1) {
    const int a = (t >= s) ? sm[t - s] : 0;
    __syncthreads();
    sm[t] += a;
    __syncthreads();
  }
  const int ex = sm[t] - v + bsum[blockIdx.x];
  off[g] = ex;
  cur[g] = ex;
}

__global__ void reorder_kernel(const int* __restrict__ ei, const int* __restrict__ et,
                               int* __restrict__ cur, int* __restrict__ sorted_src) {
  const int e = blockIdx.x * 256 + threadIdx.x;
  const int seg = ei[N_EDGES + e] * NREL + et[e];
  const int pos = atomicAdd(&cur[seg], 1);
  sorted_src[pos] = ei[e];
}

// One segment per full wave (64 lanes x uint2 = 512B/row): best load balance
// (wave time == own segment length; scheduler smooths across 160K waves).
__global__ void aggregate_kernel(const int* __restrict__ cnt, const int* __restrict__ off,
                                 const int* __restrict__ sorted_src,
                                 unsigned short* __restrict__ abf) {
  const int seg = __builtin_amdgcn_readfirstlane(blockIdx.x * 4 + (threadIdx.x >> 6));
  const int lane = threadIdx.x & 63;
  const int ne = cnt[seg];
  const int o  = off[seg];
  float a0 = 0.f, a1 = 0.f, a2 = 0.f, a3 = 0.f;
  float c0 = 0.f, c1 = 0.f, c2 = 0.f, c3 = 0.f;
  int j = 0;
  for (; j + 1 < ne; j += 2) {
    const int s0 = sorted_src[o + j];
    const int s1 = sorted_src[o + j + 1];
    const uint2 u = *(const uint2*)(abf + (size_t)s0 * KTOT + KS + lane * 4);
    const uint2 v = *(const uint2*)(abf + (size_t)s1 * KTOT + KS + lane * 4);
    a0 += bflo(u.x); a1 += bfhi(u.x); a2 += bflo(u.y); a3 += bfhi(u.y);
    c0 += bflo(v.x); c1 += bfhi(v.x); c2 += bflo(v.y); c3 += bfhi(v.y);
  }
  if (j < ne) {
    const uint2 u = *(const uint2*)(abf + (size_t)sorted_src[o + j] * KTOT + KS + lane * 4);
    a0 += bflo(u.x); a1 += bfhi(u.x); a2 += bflo(u.y); a3 += bfhi(u.y);
  }
  a0 += c0; a1 += c1; a2 += c2; a3 += c3;
  const int node = seg >> 3, r = seg & 7;
  union { unsigned short u[4]; uint2 q; } pk;
  pk.u[0] = f2bf(a0); pk.u[1] = f2bf(a1);
  pk.u[2] = f2bf(a2); pk.u[3] = f2bf(a3);
  *(uint2*)(abf + (size_t)node * KTOT + r * IN_DIM + lane * 4) = pk.q;
}

// C[20000][800] = Abf[20000][2304] @ WcatT^T + bias.
// R6 schedule verbatim; R11 change: COL-FASTEST within XCD chunk so the
// 4 col-tiles of one row panel are consecutive on the same XCD -> A panel
// (590KB) L2-resident, B (4.7MB) the re-read (L2-resident too).
__global__ __launch_bounds__(512) void gemm_kernel(
    const unsigned short* __restrict__ abf,
    const unsigned short* __restrict__ wcatT,
    const float* __restrict__ bias, float* __restrict__ out) {
  __shared__ __align__(16) char lds[3 * LBUF];

  const int lin = blockIdx.x;
  const int q8 = NWG >> 3, r8 = NWG & 7;           // 78, 4
  const int xcd = lin & 7, idx = lin >> 3;
  const int wg = (xcd < r8 ? xcd * (q8 + 1) : r8 * (q8 + 1) + (xcd - r8) * q8) + idx;
  const int row0 = (wg / NT) * BM;                 // col-fastest (R11)
  const int col0 = (wg % NT) * BN;

  const int tid = threadIdx.x;
  const int w = tid >> 6, l = tid & 63;
  const int wm = w >> 2, wn = w & 3;               // wave tile: rows wm*64, cols wn*64
  const int la = l & 15, lg = l >> 4;
  const int l3 = l >> 3;
  const int sch = (l & 7) ^ l3;                    // pre-swizzled global k-chunk (T2)

  const unsigned short* gA[2];
  const unsigned short* gB[4];
  #pragma unroll
  for (int i = 0; i < 2; ++i) {
    int ga = row0 + i * 64 + w * 8 + l3;
    ga = (ga < N_NODES) ? ga : (N_NODES - 1);      // clamp: garbage rows never stored
    gA[i] = abf + (size_t)ga * KTOT + sch * 8;
  }
  #pragma unroll
  for (int i = 0; i < 4; ++i)
    gB[i] = wcatT + (size_t)(col0 + i * 64 + w * 8 + l3) * KTOT + sch * 8;

  f32x4_t acc[4][4];
  #pragma unroll
  for (int i = 0; i < 4; ++i)
    #pragma unroll
    for (int j = 0; j < 4; ++j)
      acc[i][j] = (f32x4_t)(0.0f);

  auto stage_all = [&](int buf, int kt) {
    char* pA = lds + buf * LBUF + w * 1024;
    char* pB = pA + 16384;
    const int ko = kt * BK;
    gload16(gA[0] + ko, pA);
    gload16(gA[1] + ko, pA + 8192);
    gload16(gB[0] + ko, pB);
    gload16(gB[1] + ko, pB + 8192);
    gload16(gB[2] + ko, pB + 16384);
    gload16(gB[3] + ko, pB + 24576);
  };

  stage_all(0, 0);
  stage_all(1, 1);                                 // 12 loads in flight

  for (int kt = 0; kt < NKT; ++kt) {
    const int cbuf = kt % 3;
    const int pbuf = (kt + 2) % 3;
    const bool pf = (kt + 2) < NKT;
    const int pko = (kt + 2) * BK;
    const char* Ab = lds + cbuf * LBUF;
    const char* Bb = Ab + 16384;
    char* pA = lds + pbuf * LBUF + w * 1024;
    char* pB = pA + 16384;

    if (kt + 1 < NKT) { asm volatile("s_waitcnt vmcnt(6)" ::: "memory"); }
    else              { asm volatile("s_waitcnt vmcnt(0)" ::: "memory"); }
    __builtin_amdgcn_sched_barrier(0);
    __builtin_amdgcn_s_barrier();                  // all waves' staging visible

    short8_t af0, af1, bf0, bf1, bf2, bf3;

    // ---- phase 0: s=0, mf 0-1 ----
    {
      const int r0 = wm * 64 + la,       r1 = wm * 64 + 16 + la;
      af0 = *(const short8_t*)(Ab + r0 * 128 + ((lg << 4) ^ ((r0 & 7) << 4)));
      af1 = *(const short8_t*)(Ab + r1 * 128 + ((lg << 4) ^ ((r1 & 7) << 4)));
      #pragma unroll
      for (int nf = 0; nf < 4; ++nf) {
        const int rr = wn * 64 + nf * 16 + la;
        const short8_t v = *(const short8_t*)(Bb + rr * 128 + ((lg << 4) ^ ((rr & 7) << 4)));
        if (nf == 0) bf0 = v; else if (nf == 1) bf1 = v; else if (nf == 2) bf2 = v; else bf3 = v;
      }
      if (pf) { gload16(gA[0] + pko, pA); gload16(gA[1] + pko, pA + 8192); }
      __builtin_amdgcn_s_barrier();
      asm volatile("s_waitcnt lgkmcnt(0)" ::: "memory");
      __builtin_amdgcn_sched_barrier(0);
      __builtin_amdgcn_s_setprio(1);
      acc[0][0] = __builtin_amdgcn_mfma_f32_16x16x32_bf16(af0, bf0, acc[0][0], 0, 0, 0);
      acc[0][1] = __builtin_amdgcn_mfma_f32_16x16x32_bf16(af0, bf1, acc[0][1], 0, 0, 0);
      acc[0][2] = __builtin_amdgcn_mfma_f32_16x16x32_bf16(af0, bf2, acc[0][2], 0, 0, 0);
      acc[0][3] = __builtin_amdgcn_mfma_f32_16x16x32_bf16(af0, bf3, acc[0][3], 0, 0, 0);
      acc[1][0] = __builtin_amdgcn_mfma_f32_16x16x32_bf16(af1, bf0, acc[1][0], 0, 0, 0);
      acc[1][1] = __builtin_amdgcn_mfma_f32_16x16x32_bf16(af1, bf1, acc[1][1], 0, 0, 0);
      acc[1][2] = __builtin_amdgcn_mfma_f32_16x16x32_bf16(af1, bf2, acc[1][2], 0, 0, 0);
      acc[1][3] = __builtin_amdgcn_mfma_f32_16x16x32_bf16(af1, bf3, acc[1][3], 0, 0, 0);
      __builtin_amdgcn_s_setprio(0);
      __builtin_amdgcn_s_barrier();
    }
    // ---- phase 1: s=0, mf 2-3 ----
    {
      const int r0 = wm * 64 + 32 + la,  r1 = wm * 64 + 48 + la;
      af0 = *(const short8_t*)(Ab + r0 * 128 + ((lg << 4) ^ ((r0 & 7) << 4)));
      af1 = *(const short8_t*)(Ab + r1 * 128 + ((lg << 4) ^ ((r1 & 7) << 4)));
      if (pf) { gload16(gB[0] + pko, pB); gload16(gB[1] + pko, pB + 8192); }
      __builtin_amdgcn_s_barrier();
      asm volatile("s_waitcnt lgkmcnt(0)" ::: "memory");
      __builtin_amdgcn_sched_barrier(0);
      __builtin_amdgcn_s_setprio(1);
      acc[2][0] = __builtin_amdgcn_mfma_f32_16x16x32_bf16(af0, bf0, acc[2][0], 0, 0, 0);
      acc[2][1] = __builtin_amdgcn_mfma_f32_16x16x32_bf16(af0, bf1, acc[2][1], 0, 0, 0);
      acc[2][2] = __builtin_amdgcn_mfma_f32_16x16x32_bf16(af0, bf2, acc[2][2], 0, 0, 0);
      acc[2][3] = __builtin_amdgcn_mfma_f32_16x16x32_bf16(af0, bf3, acc[2][3], 0, 0, 0);
      acc[3][0] = __builtin_amdgcn_mfma_f32_16x16x32_bf16(af1, bf0, acc[3][0], 0, 0, 0);
      acc[3][1] = __builtin_amdgcn_mfma_f32_16x16x32_bf16(af1, bf1, acc[3][1], 0, 0, 0);
      acc[3][2] = __builtin_amdgcn_mfma_f32_16x16x32_bf16(af1, bf2, acc[3][2], 0, 0, 0);
      acc[3][3] = __builtin_amdgcn_mfma_f32_16x16x32_bf16(af1, bf3, acc[3][3], 0, 0, 0);
      __builtin_amdgcn_s_setprio(0);
      __builtin_amdgcn_s_barrier();
    }
    // ---- phase 2: s=1, mf 0-1 ----
    {
      const int r0 = wm * 64 + la,       r1 = wm * 64 + 16 + la;
      af0 = *(const short8_t*)(Ab + r0 * 128 + (((4 + lg) << 4) ^ ((r0 & 7) << 4)));
      af1 = *(const short8_t*)(Ab + r1 * 128 + (((4 + lg) << 4) ^ ((r1 & 7) << 4)));
      #pragma unroll
      for (int nf = 0; nf < 4; ++nf) {
        const int rr = wn * 64 + nf * 16 + la;
        const short8_t v = *(const short8_t*)(Bb + rr * 128 + (((4 + lg) << 4) ^ ((rr & 7) << 4)));
        if (nf == 0) bf0 = v; else if (nf == 1) bf1 = v; else if (nf == 2) bf2 = v; else bf3 = v;
      }
      if (pf) { gload16(gB[2] + pko, pB + 16384); gload16(gB[3] + pko, pB + 24576); }
      __builtin_amdgcn_s_barrier();
      asm volatile("s_waitcnt lgkmcnt(0)" ::: "memory");
      __builtin_amdgcn_sched_barrier(0);
      __builtin_amdgcn_s_setprio(1);
      acc[0][0] = __builtin_amdgcn_mfma_f32_16x16x32_bf16(af0, bf0, acc[0][0], 0, 0, 0);
      acc[0][1] = __builtin_amdgcn_mfma_f32_16x16x32_bf16(af0, bf1, acc[0][1], 0, 0, 0);
      acc[0][2] = __builtin_amdgcn_mfma_f32_16x16x32_bf16(af0, bf2, acc[0][2], 0, 0, 0);
      acc[0][3] = __builtin_amdgcn_mfma_f32_16x16x32_bf16(af0, bf3, acc[0][3], 0, 0, 0);
      acc[1][0] = __builtin_amdgcn_mfma_f32_16x16x32_bf16(af1, bf0, acc[1][0], 0, 0, 0);
      acc[1][1] = __builtin_amdgcn_mfma_f32_16x16x32_bf16(af1, bf1, acc[1][1], 0, 0, 0);
      acc[1][2] = __builtin_amdgcn_mfma_f32_16x16x32_bf16(af1, bf2, acc[1][2], 0, 0, 0);
      acc[1][3] = __builtin_amdgcn_mfma_f32_16x16x32_bf16(af1, bf3, acc[1][3], 0, 0, 0);
      __builtin_amdgcn_s_setprio(0);
      __builtin_amdgcn_s_barrier();
    }
    // ---- phase 3: s=1, mf 2-3 ----
    {
      const int r0 = wm * 64 + 32 + la,  r1 = wm * 64 + 48 + la;
      af0 = *(const short8_t*)(Ab + r0 * 128 + (((4 + lg) << 4) ^ ((r0 & 7) << 4)));
      af1 = *(const short8_t*)(Ab + r1 * 128 + (((4 + lg) << 4) ^ ((r1 & 7) << 4)));
      __builtin_amdgcn_s_barrier();
      asm volatile("s_waitcnt lgkmcnt(0)" ::: "memory");
      __builtin_amdgcn_sched_barrier(0);
      __builtin_amdgcn_s_setprio(1);
      acc[2][0] = __builtin_amdgcn_mfma_f32_16x16x32_bf16(af0, bf0, acc[2][0], 0, 0, 0);
      acc[2][1] = __builtin_amdgcn_mfma_f32_16x16x32_bf16(af0, bf1, acc[2][1], 0, 0, 0);
      acc[2][2] = __builtin_amdgcn_mfma_f32_16x16x32_bf16(af0, bf2, acc[2][2], 0, 0, 0);
      acc[2][3] = __builtin_amdgcn_mfma_f32_16x16x32_bf16(af0, bf3, acc[2][3], 0, 0, 0);
      acc[3][0] = __builtin_amdgcn_mfma_f32_16x16x32_bf16(af1, bf0, acc[3][0], 0, 0, 0);
      acc[3][1] = __builtin_amdgcn_mfma_f32_16x16x32_bf16(af1, bf1, acc[3][1], 0, 0, 0);
      acc[3][2] = __builtin_amdgcn_mfma_f32_16x16x32_bf16(af1, bf2, acc[3][2], 0, 0, 0);
      acc[3][3] = __builtin_amdgcn_mfma_f32_16x16x32_bf16(af1, bf3, acc[3][3], 0, 0, 0);
      __builtin_amdgcn_s_setprio(0);
      __builtin_amdgcn_s_barrier();
    }
  }

  #pragma unroll
  for (int nf = 0; nf < 4; ++nf) {
    const int gcol = col0 + wn * 64 + nf * 16 + la;
    if (gcol < OUT_DIM) {
      const float bv = bias[gcol];
      #pragma unroll
      for (int f = 0; f < 4; ++f) {
        const int gr0 = row0 + wm * 64 + f * 16 + lg * 4;
        #pragma unroll
        for (int j = 0; j < 4; ++j) {
          const int gr = gr0 + j;
          if (gr < N_NODES)
            out[(size_t)gr * OUT_DIM + gcol] = acc[f][nf][j] + bv;
        }
      }
    }
  }
}

extern "C" void kernel_launch(void* const* d_in, const int* in_sizes, int n_in,
                              void* d_out, int out_size, void* d_ws, size_t ws_size,
                              hipStream_t stream) {
  const float* x     = (const float*)d_in[0];
  const int*   ei    = (const int*)d_in[1];
  const int*   et    = (const int*)d_in[2];
  const float* bases = (const float*)d_in[3];
  const float* att   = (const float*)d_in[4];
  const float* root  = (const float*)d_in[5];
  const float* bias  = (const float*)d_in[6];
  float* out = (float*)d_out;

  char* p = (char*)d_ws;
  unsigned short* abf   = (unsigned short*)p;  p += (size_t)N_NODES * KTOT * 2;  // 92,160,000
  unsigned short* wcatT = (unsigned short*)p;  p += (size_t)NPAD * KTOT * 2;     //  4,718,592
  int* cnt        = (int*)p;                   p += (size_t)NSEG * 4;
  int* off        = (int*)p;                   p += (size_t)NSEG * 4;
  int* cur        = (int*)p;                   p += (size_t)NSEG * 4;
  int* sorted_src = (int*)p;                   p += (size_t)N_EDGES * 4;
  int* bsum       = (int*)p;                   p += 4096;

  init_kernel<<<INIT_NWG, 256, 0, stream>>>(x, bases, att, root, cnt, abf, wcatT);
  hist_kernel<<<N_EDGES / 256, 256, 0, stream>>>(ei, et, cnt);
  scan_reduce_kernel<<<NB, 256, 0, stream>>>(cnt, bsum);
  scan_bsum_kernel<<<1, 1024, 0, stream>>>(bsum);
  scan_final_kernel<<<NB, 256, 0, stream>>>(cnt, bsum, off, cur);
  reorder_kernel<<<N_EDGES / 256, 256, 0, stream>>>(ei, et, cur, sorted_src);
  aggregate_kernel<<<NSEG / 4, 256, 0, stream>>>(cnt, off, sorted_src, abf);
  gemm_kernel<<<NWG, 512, 0, stream>>>(abf, wcatT, bias, out);
}

// Round 12
// 257.760 us; speedup vs baseline: 1.1388x; 1.1388x over previous
//
#include <hip/hip_runtime.h>

// RGCNConv basis-decomposed, sort-based aggregation + 8-phase pipelined bf16 MFMA GEMM.
//   Abf = [seg_sum(bf16(x)[src] by (dst,rel)) | bf16(x)]  (bf16, [N][2304])
//   out = Abf @ WcatT^T + bias                            (f32 out)
// R12: aggregate = 1 seg/wave, half-wave edge split (uint4, 1024B/instr) + shfl
// combine; wcat build with coalesced bases reads; GEMM = R11 (col-fastest).

#define N_NODES 20000
#define N_EDGES 640000
#define IN_DIM  256
#define OUT_DIM 800
#define NREL    8
#define NSEG    160000          // N_NODES * NREL
#define KS      2048            // NREL * IN_DIM
#define KTOT    2304            // KS + IN_DIM
#define NPAD    1024            // padded N for GEMM B (4 x 256)
#define NB      625             // NSEG / 256 scan blocks

// GEMM geometry: 128x256 tile, BK=64, 8 waves (2Mx4N, 64x64), triple-buffer LDS
#define BM 128
#define BN 256
#define BK 64
#define NKT (KTOT / BK)         // 36
#define MT  157                 // ceil(20000/128)
#define NT  4                   // 1024/256
#define NWG (MT * NT)           // 628
#define LBUF 49152              // per K-tile: A 16K | B 32K

// fused init kernel block ranges
#define XCAST_B (N_NODES * 64 / 256)          // 5000
#define WCAT_B  ((KTOT / 8) * 4)              // 288 k-chunks x 4 n-groups = 1152
#define INIT_NWG (NB + XCAST_B + WCAT_B)      // 6777

typedef float f32x4_t __attribute__((ext_vector_type(4)));
typedef short short8_t __attribute__((ext_vector_type(8)));

__device__ __forceinline__ unsigned short f2bf(float f) {
  unsigned u = __float_as_uint(f);
  u += 0x7fffu + ((u >> 16) & 1u);
  return (unsigned short)(u >> 16);
}

__device__ __forceinline__ float bflo(unsigned w) { return __uint_as_float(w << 16); }
__device__ __forceinline__ float bfhi(unsigned w) { return __uint_as_float(w & 0xffff0000u); }

__device__ __forceinline__ void gload16(const void* g, void* l) {
  __builtin_amdgcn_global_load_lds(
      (const __attribute__((address_space(1))) void*)g,
      (__attribute__((address_space(3))) void*)l, 16, 0, 0);
}

// ---------------- fused init: zero cnt | xcast | build_wcat ----------------
__global__ void init_kernel(const float* __restrict__ x,
                            const float* __restrict__ bases,
                            const float* __restrict__ att,
                            const float* __restrict__ root,
                            int* __restrict__ cnt,
                            unsigned short* __restrict__ abf,
                            unsigned short* __restrict__ wcatT) {
  const int b = blockIdx.x;
  const int t = threadIdx.x;
  if (b < NB) {
    cnt[b * 256 + t] = 0;
  } else if (b < NB + XCAST_B) {
    const int id = (b - NB) * 256 + t;           // 20000*64
    const int row = id >> 6, lane = id & 63;
    const float4 v = ((const float4*)x)[(size_t)row * 64 + lane];
    union { unsigned short u[4]; uint2 q; } pk;
    pk.u[0] = f2bf(v.x); pk.u[1] = f2bf(v.y);
    pk.u[2] = f2bf(v.z); pk.u[3] = f2bf(v.w);
    *(uint2*)(abf + (size_t)row * KTOT + KS + lane * 4) = pk.q;
  } else {
    // wcat: block covers 8 consecutive k's x 256 consecutive n's.
    // Lanes run over n -> bases reads COALESCED (old: 25.6KB inter-lane stride).
    const int rem = b - NB - XCAST_B;            // 0..1151
    const int kc = rem >> 2, ng = rem & 3;
    const int k0 = kc * 8;                       // 0..2296
    const int n  = ng * 256 + t;                 // 0..1023
    union { unsigned short u[8]; uint4 q; } pk;
    if (n >= OUT_DIM) {
      pk.q = make_uint4(0u, 0u, 0u, 0u);
    } else if (k0 < KS) {
      const int r = k0 >> 8, i0 = k0 & 255;
      float av[8];
      #pragma unroll
      for (int bb = 0; bb < 8; ++bb) av[bb] = att[r * 8 + bb];
      #pragma unroll
      for (int j = 0; j < 8; ++j) {
        float v = 0.f;
        #pragma unroll
        for (int bb = 0; bb < 8; ++bb)
          v += av[bb] * bases[((size_t)bb * IN_DIM + i0 + j) * OUT_DIM + n];
        pk.u[j] = f2bf(v);
      }
    } else {
      #pragma unroll
      for (int j = 0; j < 8; ++j)
        pk.u[j] = f2bf(root[(size_t)(k0 - KS + j) * OUT_DIM + n]);
    }
    *(uint4*)(wcatT + (size_t)n * KTOT + k0) = pk.q;
  }
}

// ---------------- sort pipeline ----------------

__global__ void hist_kernel(const int* __restrict__ ei, const int* __restrict__ et,
                            int* __restrict__ cnt) {
  const int e = blockIdx.x * 256 + threadIdx.x;
  const int seg = ei[N_EDGES + e] * NREL + et[e];
  atomicAdd(&cnt[seg], 1);
}

__global__ void scan_reduce_kernel(const int* __restrict__ cnt, int* __restrict__ bsum) {
  __shared__ int sm[256];
  const int t = threadIdx.x;
  sm[t] = cnt[blockIdx.x * 256 + t];
  __syncthreads();
  for (int s = 128; s > 0; s >>= 1) {
    if (t < s) sm[t] += sm[t + s];
    __syncthreads();
  }
  if (t == 0) bsum[blockIdx.x] = sm[0];
}

__global__ void scan_bsum_kernel(int* __restrict__ bsum) {
  __shared__ int sm[1024];
  const int t = threadIdx.x;
  const int v = (t < NB) ? bsum[t] : 0;
  sm[t] = v;
  __syncthreads();
  for (int s = 1; s < 1024; s <<= 1) {
    const int a = (t >= s) ? sm[t - s] : 0;
    __syncthreads();
    sm[t] += a;
    __syncthreads();
  }
  if (t < NB) bsum[t] = sm[t] - v;   // exclusive
}

__global__ void scan_final_kernel(const int* __restrict__ cnt, const int* __restrict__ bsum,
                                  int* __restrict__ off, int* __restrict__ cur) {
  __shared__ int sm[256];
  const int t = threadIdx.x;
  const int g = blockIdx.x * 256 + t;
  const int v = cnt[g];
  sm[t] = v;
  __syncthreads();
  for (int s = 1; s < 256; s <<= 1) {
    const int a = (t >= s) ? sm[t - s] : 0;
    __syncthreads();
    sm[t] += a;
    __syncthreads();
  }
  const int ex = sm[t] - v + bsum[blockIdx.x];
  off[g] = ex;
  cur[g] = ex;
}

__global__ void reorder_kernel(const int* __restrict__ ei, const int* __restrict__ et,
                               int* __restrict__ cur, int* __restrict__ sorted_src) {
  const int e = blockIdx.x * 256 + threadIdx.x;
  const int seg = ei[N_EDGES + e] * NREL + et[e];
  const int pos = atomicAdd(&cur[seg], 1);
  sorted_src[pos] = ei[e];
}

// One segment per wave; half-wave h loads edge j+h (uint4 x 32 lanes = two
// 512B rows per load instruction, like R10) -> perfectly balanced (time = own
// ne) with R10's bytes/instr.  Halves combined via shfl_xor(32); lanes 0-31 store.
__global__ void aggregate_kernel(const int* __restrict__ cnt, const int* __restrict__ off,
                                 const int* __restrict__ sorted_src,
                                 unsigned short* __restrict__ abf) {
  const int seg = __builtin_amdgcn_readfirstlane(blockIdx.x * 4 + (threadIdx.x >> 6));
  const int l = threadIdx.x & 63;
  const int half = l >> 5;
  const int sl = l & 31;
  const int ne = cnt[seg];
  const int o  = off[seg];
  float a0 = 0.f, a1 = 0.f, a2 = 0.f, a3 = 0.f;
  float a4 = 0.f, a5 = 0.f, a6 = 0.f, a7 = 0.f;
  int j = 0;
  for (; j + 2 <= ne; j += 2) {
    const int s = sorted_src[o + j + half];
    const uint4 u = *(const uint4*)(abf + (size_t)s * KTOT + KS + sl * 8);
    a0 += bflo(u.x); a1 += bfhi(u.x); a2 += bflo(u.y); a3 += bfhi(u.y);
    a4 += bflo(u.z); a5 += bfhi(u.z); a6 += bflo(u.w); a7 += bfhi(u.w);
  }
  if (j < ne && half == 0) {                     // odd tail: half 0 only
    const int s = sorted_src[o + j];
    const uint4 u = *(const uint4*)(abf + (size_t)s * KTOT + KS + sl * 8);
    a0 += bflo(u.x); a1 += bfhi(u.x); a2 += bflo(u.y); a3 += bfhi(u.y);
    a4 += bflo(u.z); a5 += bfhi(u.z); a6 += bflo(u.w); a7 += bfhi(u.w);
  }
  a0 += __shfl_xor(a0, 32); a1 += __shfl_xor(a1, 32);
  a2 += __shfl_xor(a2, 32); a3 += __shfl_xor(a3, 32);
  a4 += __shfl_xor(a4, 32); a5 += __shfl_xor(a5, 32);
  a6 += __shfl_xor(a6, 32); a7 += __shfl_xor(a7, 32);
  if (half == 0) {
    const int node = seg >> 3, r = seg & 7;
    union { unsigned short u[8]; uint4 q; } pk;
    pk.u[0] = f2bf(a0); pk.u[1] = f2bf(a1); pk.u[2] = f2bf(a2); pk.u[3] = f2bf(a3);
    pk.u[4] = f2bf(a4); pk.u[5] = f2bf(a5); pk.u[6] = f2bf(a6); pk.u[7] = f2bf(a7);
    *(uint4*)(abf + (size_t)node * KTOT + r * IN_DIM + sl * 8) = pk.q;
  }
}

// C[20000][800] = Abf[20000][2304] @ WcatT^T + bias.
// R6 schedule verbatim; col-fastest XCD ordering (R11: A-panel L2-resident).
__global__ __launch_bounds__(512) void gemm_kernel(
    const unsigned short* __restrict__ abf,
    const unsigned short* __restrict__ wcatT,
    const float* __restrict__ bias, float* __restrict__ out) {
  __shared__ __align__(16) char lds[3 * LBUF];

  const int lin = blockIdx.x;
  const int q8 = NWG >> 3, r8 = NWG & 7;           // 78, 4
  const int xcd = lin & 7, idx = lin >> 3;
  const int wg = (xcd < r8 ? xcd * (q8 + 1) : r8 * (q8 + 1) + (xcd - r8) * q8) + idx;
  const int row0 = (wg / NT) * BM;                 // col-fastest
  const int col0 = (wg % NT) * BN;

  const int tid = threadIdx.x;
  const int w = tid >> 6, l = tid & 63;
  const int wm = w >> 2, wn = w & 3;               // wave tile: rows wm*64, cols wn*64
  const int la = l & 15, lg = l >> 4;
  const int l3 = l >> 3;
  const int sch = (l & 7) ^ l3;                    // pre-swizzled global k-chunk (T2)

  const unsigned short* gA[2];
  const unsigned short* gB[4];
  #pragma unroll
  for (int i = 0; i < 2; ++i) {
    int ga = row0 + i * 64 + w * 8 + l3;
    ga = (ga < N_NODES) ? ga : (N_NODES - 1);      // clamp: garbage rows never stored
    gA[i] = abf + (size_t)ga * KTOT + sch * 8;
  }
  #pragma unroll
  for (int i = 0; i < 4; ++i)
    gB[i] = wcatT + (size_t)(col0 + i * 64 + w * 8 + l3) * KTOT + sch * 8;

  f32x4_t acc[4][4];
  #pragma unroll
  for (int i = 0; i < 4; ++i)
    #pragma unroll
    for (int j = 0; j < 4; ++j)
      acc[i][j] = (f32x4_t)(0.0f);

  auto stage_all = [&](int buf, int kt) {
    char* pA = lds + buf * LBUF + w * 1024;
    char* pB = pA + 16384;
    const int ko = kt * BK;
    gload16(gA[0] + ko, pA);
    gload16(gA[1] + ko, pA + 8192);
    gload16(gB[0] + ko, pB);
    gload16(gB[1] + ko, pB + 8192);
    gload16(gB[2] + ko, pB + 16384);
    gload16(gB[3] + ko, pB + 24576);
  };

  stage_all(0, 0);
  stage_all(1, 1);                                 // 12 loads in flight

  for (int kt = 0; kt < NKT; ++kt) {
    const int cbuf = kt % 3;
    const int pbuf = (kt + 2) % 3;
    const bool pf = (kt + 2) < NKT;
    const int pko = (kt + 2) * BK;
    const char* Ab = lds + cbuf * LBUF;
    const char* Bb = Ab + 16384;
    char* pA = lds + pbuf * LBUF + w * 1024;
    char* pB = pA + 16384;

    if (kt + 1 < NKT) { asm volatile("s_waitcnt vmcnt(6)" ::: "memory"); }
    else              { asm volatile("s_waitcnt vmcnt(0)" ::: "memory"); }
    __builtin_amdgcn_sched_barrier(0);
    __builtin_amdgcn_s_barrier();                  // all waves' staging visible

    short8_t af0, af1, bf0, bf1, bf2, bf3;

    // ---- phase 0: s=0, mf 0-1 ----
    {
      const int r0 = wm * 64 + la,       r1 = wm * 64 + 16 + la;
      af0 = *(const short8_t*)(Ab + r0 * 128 + ((lg << 4) ^ ((r0 & 7) << 4)));
      af1 = *(const short8_t*)(Ab + r1 * 128 + ((lg << 4) ^ ((r1 & 7) << 4)));
      #pragma unroll
      for (int nf = 0; nf < 4; ++nf) {
        const int rr = wn * 64 + nf * 16 + la;
        const short8_t v = *(const short8_t*)(Bb + rr * 128 + ((lg << 4) ^ ((rr & 7) << 4)));
        if (nf == 0) bf0 = v; else if (nf == 1) bf1 = v; else if (nf == 2) bf2 = v; else bf3 = v;
      }
      if (pf) { gload16(gA[0] + pko, pA); gload16(gA[1] + pko, pA + 8192); }
      __builtin_amdgcn_s_barrier();
      asm volatile("s_waitcnt lgkmcnt(0)" ::: "memory");
      __builtin_amdgcn_sched_barrier(0);
      __builtin_amdgcn_s_setprio(1);
      acc[0][0] = __builtin_amdgcn_mfma_f32_16x16x32_bf16(af0, bf0, acc[0][0], 0, 0, 0);
      acc[0][1] = __builtin_amdgcn_mfma_f32_16x16x32_bf16(af0, bf1, acc[0][1], 0, 0, 0);
      acc[0][2] = __builtin_amdgcn_mfma_f32_16x16x32_bf16(af0, bf2, acc[0][2], 0, 0, 0);
      acc[0][3] = __builtin_amdgcn_mfma_f32_16x16x32_bf16(af0, bf3, acc[0][3], 0, 0, 0);
      acc[1][0] = __builtin_amdgcn_mfma_f32_16x16x32_bf16(af1, bf0, acc[1][0], 0, 0, 0);
      acc[1][1] = __builtin_amdgcn_mfma_f32_16x16x32_bf16(af1, bf1, acc[1][1], 0, 0, 0);
      acc[1][2] = __builtin_amdgcn_mfma_f32_16x16x32_bf16(af1, bf2, acc[1][2], 0, 0, 0);
      acc[1][3] = __builtin_amdgcn_mfma_f32_16x16x32_bf16(af1, bf3, acc[1][3], 0, 0, 0);
      __builtin_amdgcn_s_setprio(0);
      __builtin_amdgcn_s_barrier();
    }
    // ---- phase 1: s=0, mf 2-3 ----
    {
      const int r0 = wm * 64 + 32 + la,  r1 = wm * 64 + 48 + la;
      af0 = *(const short8_t*)(Ab + r0 * 128 + ((lg << 4) ^ ((r0 & 7) << 4)));
      af1 = *(const short8_t*)(Ab + r1 * 128 + ((lg << 4) ^ ((r1 & 7) << 4)));
      if (pf) { gload16(gB[0] + pko, pB); gload16(gB[1] + pko, pB + 8192); }
      __builtin_amdgcn_s_barrier();
      asm volatile("s_waitcnt lgkmcnt(0)" ::: "memory");
      __builtin_amdgcn_sched_barrier(0);
      __builtin_amdgcn_s_setprio(1);
      acc[2][0] = __builtin_amdgcn_mfma_f32_16x16x32_bf16(af0, bf0, acc[2][0], 0, 0, 0);
      acc[2][1] = __builtin_amdgcn_mfma_f32_16x16x32_bf16(af0, bf1, acc[2][1], 0, 0, 0);
      acc[2][2] = __builtin_amdgcn_mfma_f32_16x16x32_bf16(af0, bf2, acc[2][2], 0, 0, 0);
      acc[2][3] = __builtin_amdgcn_mfma_f32_16x16x32_bf16(af0, bf3, acc[2][3], 0, 0, 0);
      acc[3][0] = __builtin_amdgcn_mfma_f32_16x16x32_bf16(af1, bf0, acc[3][0], 0, 0, 0);
      acc[3][1] = __builtin_amdgcn_mfma_f32_16x16x32_bf16(af1, bf1, acc[3][1], 0, 0, 0);
      acc[3][2] = __builtin_amdgcn_mfma_f32_16x16x32_bf16(af1, bf2, acc[3][2], 0, 0, 0);
      acc[3][3] = __builtin_amdgcn_mfma_f32_16x16x32_bf16(af1, bf3, acc[3][3], 0, 0, 0);
      __builtin_amdgcn_s_setprio(0);
      __builtin_amdgcn_s_barrier();
    }
    // ---- phase 2: s=1, mf 0-1 ----
    {
      const int r0 = wm * 64 + la,       r1 = wm * 64 + 16 + la;
      af0 = *(const short8_t*)(Ab + r0 * 128 + (((4 + lg) << 4) ^ ((r0 & 7) << 4)));
      af1 = *(const short8_t*)(Ab + r1 * 128 + (((4 + lg) << 4) ^ ((r1 & 7) << 4)));
      #pragma unroll
      for (int nf = 0; nf < 4; ++nf) {
        const int rr = wn * 64 + nf * 16 + la;
        const short8_t v = *(const short8_t*)(Bb + rr * 128 + (((4 + lg) << 4) ^ ((rr & 7) << 4)));
        if (nf == 0) bf0 = v; else if (nf == 1) bf1 = v; else if (nf == 2) bf2 = v; else bf3 = v;
      }
      if (pf) { gload16(gB[2] + pko, pB + 16384); gload16(gB[3] + pko, pB + 24576); }
      __builtin_amdgcn_s_barrier();
      asm volatile("s_waitcnt lgkmcnt(0)" ::: "memory");
      __builtin_amdgcn_sched_barrier(0);
      __builtin_amdgcn_s_setprio(1);
      acc[0][0] = __builtin_amdgcn_mfma_f32_16x16x32_bf16(af0, bf0, acc[0][0], 0, 0, 0);
      acc[0][1] = __builtin_amdgcn_mfma_f32_16x16x32_bf16(af0, bf1, acc[0][1], 0, 0, 0);
      acc[0][2] = __builtin_amdgcn_mfma_f32_16x16x32_bf16(af0, bf2, acc[0][2], 0, 0, 0);
      acc[0][3] = __builtin_amdgcn_mfma_f32_16x16x32_bf16(af0, bf3, acc[0][3], 0, 0, 0);
      acc[1][0] = __builtin_amdgcn_mfma_f32_16x16x32_bf16(af1, bf0, acc[1][0], 0, 0, 0);
      acc[1][1] = __builtin_amdgcn_mfma_f32_16x16x32_bf16(af1, bf1, acc[1][1], 0, 0, 0);
      acc[1][2] = __builtin_amdgcn_mfma_f32_16x16x32_bf16(af1, bf2, acc[1][2], 0, 0, 0);
      acc[1][3] = __builtin_amdgcn_mfma_f32_16x16x32_bf16(af1, bf3, acc[1][3], 0, 0, 0);
      __builtin_amdgcn_s_setprio(0);
      __builtin_amdgcn_s_barrier();
    }
    // ---- phase 3: s=1, mf 2-3 ----
    {
      const int r0 = wm * 64 + 32 + la,  r1 = wm * 64 + 48 + la;
      af0 = *(const short8_t*)(Ab + r0 * 128 + (((4 + lg) << 4) ^ ((r0 & 7) << 4)));
      af1 = *(const short8_t*)(Ab + r1 * 128 + (((4 + lg) << 4) ^ ((r1 & 7) << 4)));
      __builtin_amdgcn_s_barrier();
      asm volatile("s_waitcnt lgkmcnt(0)" ::: "memory");
      __builtin_amdgcn_sched_barrier(0);
      __builtin_amdgcn_s_setprio(1);
      acc[2][0] = __builtin_amdgcn_mfma_f32_16x16x32_bf16(af0, bf0, acc[2][0], 0, 0, 0);
      acc[2][1] = __builtin_amdgcn_mfma_f32_16x16x32_bf16(af0, bf1, acc[2][1], 0, 0, 0);
      acc[2][2] = __builtin_amdgcn_mfma_f32_16x16x32_bf16(af0, bf2, acc[2][2], 0, 0, 0);
      acc[2][3] = __builtin_amdgcn_mfma_f32_16x16x32_bf16(af0, bf3, acc[2][3], 0, 0, 0);
      acc[3][0] = __builtin_amdgcn_mfma_f32_16x16x32_bf16(af1, bf0, acc[3][0], 0, 0, 0);
      acc[3][1] = __builtin_amdgcn_mfma_f32_16x16x32_bf16(af1, bf1, acc[3][1], 0, 0, 0);
      acc[3][2] = __builtin_amdgcn_mfma_f32_16x16x32_bf16(af1, bf2, acc[3][2], 0, 0, 0);
      acc[3][3] = __builtin_amdgcn_mfma_f32_16x16x32_bf16(af1, bf3, acc[3][3], 0, 0, 0);
      __builtin_amdgcn_s_setprio(0);
      __builtin_amdgcn_s_barrier();
    }
  }

  #pragma unroll
  for (int nf = 0; nf < 4; ++nf) {
    const int gcol = col0 + wn * 64 + nf * 16 + la;
    if (gcol < OUT_DIM) {
      const float bv = bias[gcol];
      #pragma unroll
      for (int f = 0; f < 4; ++f) {
        const int gr0 = row0 + wm * 64 + f * 16 + lg * 4;
        #pragma unroll
        for (int j = 0; j < 4; ++j) {
          const int gr = gr0 + j;
          if (gr < N_NODES)
            out[(size_t)gr * OUT_DIM + gcol] = acc[f][nf][j] + bv;
        }
      }
    }
  }
}

extern "C" void kernel_launch(void* const* d_in, const int* in_sizes, int n_in,
                              void* d_out, int out_size, void* d_ws, size_t ws_size,
                              hipStream_t stream) {
  const float* x     = (const float*)d_in[0];
  const int*   ei    = (const int*)d_in[1];
  const int*   et    = (const int*)d_in[2];
  const float* bases = (const float*)d_in[3];
  const float* att   = (const float*)d_in[4];
  const float* root  = (const float*)d_in[5];
  const float* bias  = (const float*)d_in[6];
  float* out = (float*)d_out;

  char* p = (char*)d_ws;
  unsigned short* abf   = (unsigned short*)p;  p += (size_t)N_NODES * KTOT * 2;  // 92,160,000
  unsigned short* wcatT = (unsigned short*)p;  p += (size_t)NPAD * KTOT * 2;     //  4,718,592
  int* cnt        = (int*)p;                   p += (size_t)NSEG * 4;
  int* off        = (int*)p;                   p += (size_t)NSEG * 4;
  int* cur        = (int*)p;                   p += (size_t)NSEG * 4;
  int* sorted_src = (int*)p;                   p += (size_t)N_EDGES * 4;
  int* bsum       = (int*)p;                   p += 4096;

  init_kernel<<<INIT_NWG, 256, 0, stream>>>(x, bases, att, root, cnt, abf, wcatT);
  hist_kernel<<<N_EDGES / 256, 256, 0, stream>>>(ei, et, cnt);
  scan_reduce_kernel<<<NB, 256, 0, stream>>>(cnt, bsum);
  scan_bsum_kernel<<<1, 1024, 0, stream>>>(bsum);
  scan_final_kernel<<<NB, 256, 0, stream>>>(cnt, bsum, off, cur);
  reorder_kernel<<<N_EDGES / 256, 256, 0, stream>>>(ei, et, cur, sorted_src);
  aggregate_kernel<<<NSEG / 4, 256, 0, stream>>>(cnt, off, sorted_src, abf);
  gemm_kernel<<<NWG, 512, 0, stream>>>(abf, wcatT, bias, out);
}

// Round 13
// 241.785 us; speedup vs baseline: 1.2140x; 1.0661x over previous
//
#include <hip/hip_runtime.h>

// RGCNConv basis-decomposed, sort-based aggregation + 4-phase pipelined bf16 MFMA GEMM.
//   Abf = [seg_sum(bf16(x)[src] by (dst,rel)) | bf16(x)]  (bf16, [N][2304])
//   out = Abf @ WcatT^T + bias                            (f32 out)
// R13: GEMM tile 256x160 (zero col-padding, NWG=395 -> 2 rounds at 1 block/CU),
// same R6 phase schedule; waves 4Mx2N of 64x80; 7 loads/thread/tile, vmcnt(7).

#define N_NODES 20000
#define N_EDGES 640000
#define IN_DIM  256
#define OUT_DIM 800
#define NREL    8
#define NSEG    160000          // N_NODES * NREL
#define KS      2048            // NREL * IN_DIM
#define KTOT    2304            // KS + IN_DIM
#define NPAD    1024            // wcat build grid cover (stores clipped to 800)
#define NB      625             // NSEG / 256 scan blocks

// GEMM geometry: 256x160 tile, BK=64, 8 waves (4Mx2N, 64x80 each)
#define BM 256
#define BN 160
#define BK 64
#define NKT (KTOT / BK)         // 36
#define MT  79                  // ceil(20000/256)
#define NT  5                   // 800/160, exact
#define NWG (MT * NT)           // 395
#define ABYTES 32768            // A region: 256 rows x 128B
#define LBUF 53248              // + B region: 160 rows x 128B = 20480

// fused init kernel block ranges
#define XCAST_B (N_NODES * 64 / 256)          // 5000
#define WCAT_B  ((KTOT / 8) * 4)              // 1152
#define INIT_NWG (NB + XCAST_B + WCAT_B)      // 6777

typedef float f32x4_t __attribute__((ext_vector_type(4)));
typedef short short8_t __attribute__((ext_vector_type(8)));

__device__ __forceinline__ unsigned short f2bf(float f) {
  unsigned u = __float_as_uint(f);
  u += 0x7fffu + ((u >> 16) & 1u);
  return (unsigned short)(u >> 16);
}

__device__ __forceinline__ float bflo(unsigned w) { return __uint_as_float(w << 16); }
__device__ __forceinline__ float bfhi(unsigned w) { return __uint_as_float(w & 0xffff0000u); }

__device__ __forceinline__ void gload16(const void* g, void* l) {
  __builtin_amdgcn_global_load_lds(
      (const __attribute__((address_space(1))) void*)g,
      (__attribute__((address_space(3))) void*)l, 16, 0, 0);
}

// ---------------- fused init: zero cnt | xcast | build_wcat ----------------
__global__ void init_kernel(const float* __restrict__ x,
                            const float* __restrict__ bases,
                            const float* __restrict__ att,
                            const float* __restrict__ root,
                            int* __restrict__ cnt,
                            unsigned short* __restrict__ abf,
                            unsigned short* __restrict__ wcatT) {
  const int b = blockIdx.x;
  const int t = threadIdx.x;
  if (b < NB) {
    cnt[b * 256 + t] = 0;
  } else if (b < NB + XCAST_B) {
    const int id = (b - NB) * 256 + t;           // 20000*64
    const int row = id >> 6, lane = id & 63;
    const float4 v = ((const float4*)x)[(size_t)row * 64 + lane];
    union { unsigned short u[4]; uint2 q; } pk;
    pk.u[0] = f2bf(v.x); pk.u[1] = f2bf(v.y);
    pk.u[2] = f2bf(v.z); pk.u[3] = f2bf(v.w);
    *(uint2*)(abf + (size_t)row * KTOT + KS + lane * 4) = pk.q;
  } else {
    // wcat: 8 consecutive k's x 256 consecutive n's; lanes over n -> coalesced.
    const int rem = b - NB - XCAST_B;            // 0..1151
    const int kc = rem >> 2, ng = rem & 3;
    const int k0 = kc * 8;
    const int n  = ng * 256 + t;                 // 0..1023
    if (n >= OUT_DIM) return;                    // GEMM reads only rows < 800
    union { unsigned short u[8]; uint4 q; } pk;
    if (k0 < KS) {
      const int r = k0 >> 8, i0 = k0 & 255;
      float av[8];
      #pragma unroll
      for (int bb = 0; bb < 8; ++bb) av[bb] = att[r * 8 + bb];
      #pragma unroll
      for (int j = 0; j < 8; ++j) {
        float v = 0.f;
        #pragma unroll
        for (int bb = 0; bb < 8; ++bb)
          v += av[bb] * bases[((size_t)bb * IN_DIM + i0 + j) * OUT_DIM + n];
        pk.u[j] = f2bf(v);
      }
    } else {
      #pragma unroll
      for (int j = 0; j < 8; ++j)
        pk.u[j] = f2bf(root[(size_t)(k0 - KS + j) * OUT_DIM + n]);
    }
    *(uint4*)(wcatT + (size_t)n * KTOT + k0) = pk.q;
  }
}

// ---------------- sort pipeline ----------------

__global__ void hist_kernel(const int* __restrict__ ei, const int* __restrict__ et,
                            int* __restrict__ cnt) {
  const int e = blockIdx.x * 256 + threadIdx.x;
  const int seg = ei[N_EDGES + e] * NREL + et[e];
  atomicAdd(&cnt[seg], 1);
}

__global__ void scan_reduce_kernel(const int* __restrict__ cnt, int* __restrict__ bsum) {
  __shared__ int sm[256];
  const int t = threadIdx.x;
  sm[t] = cnt[blockIdx.x * 256 + t];
  __syncthreads();
  for (int s = 128; s > 0; s >>= 1) {
    if (t < s) sm[t] += sm[t + s];
    __syncthreads();
  }
  if (t == 0) bsum[blockIdx.x] = sm[0];
}

__global__ void scan_bsum_kernel(int* __restrict__ bsum) {
  __shared__ int sm[1024];
  const int t = threadIdx.x;
  const int v = (t < NB) ? bsum[t] : 0;
  sm[t] = v;
  __syncthreads();
  for (int s = 1; s < 1024; s <<= 1) {
    const int a = (t >= s) ? sm[t - s] : 0;
    __syncthreads();
    sm[t] += a;
    __syncthreads();
  }
  if (t < NB) bsum[t] = sm[t] - v;   // exclusive
}

__global__ void scan_final_kernel(const int* __restrict__ cnt, const int* __restrict__ bsum,
                                  int* __restrict__ off, int* __restrict__ cur) {
  __shared__ int sm[256];
  const int t = threadIdx.x;
  const int g = blockIdx.x * 256 + t;
  const int v = cnt[g];
  sm[t] = v;
  __syncthreads();
  for (int s = 1; s < 256; s <<= 1) {
    const int a = (t >= s) ? sm[t - s] : 0;
    __syncthreads();
    sm[t] += a;
    __syncthreads();
  }
  const int ex = sm[t] - v + bsum[blockIdx.x];
  off[g] = ex;
  cur[g] = ex;
}

__global__ void reorder_kernel(const int* __restrict__ ei, const int* __restrict__ et,
                               int* __restrict__ cur, int* __restrict__ sorted_src) {
  const int e = blockIdx.x * 256 + threadIdx.x;
  const int seg = ei[N_EDGES + e] * NREL + et[e];
  const int pos = atomicAdd(&cur[seg], 1);
  sorted_src[pos] = ei[e];
}

// One segment per wave; half-wave h loads edge j+h (uint4 x 32 lanes = two
// 512B rows per load instruction); shfl_xor(32) combine; lanes 0-31 store.
__global__ void aggregate_kernel(const int* __restrict__ cnt, const int* __restrict__ off,
                                 const int* __restrict__ sorted_src,
                                 unsigned short* __restrict__ abf) {
  const int seg = __builtin_amdgcn_readfirstlane(blockIdx.x * 4 + (threadIdx.x >> 6));
  const int l = threadIdx.x & 63;
  const int half = l >> 5;
  const int sl = l & 31;
  const int ne = cnt[seg];
  const int o  = off[seg];
  float a0 = 0.f, a1 = 0.f, a2 = 0.f, a3 = 0.f;
  float a4 = 0.f, a5 = 0.f, a6 = 0.f, a7 = 0.f;
  int j = 0;
  for (; j + 2 <= ne; j += 2) {
    const int s = sorted_src[o + j + half];
    const uint4 u = *(const uint4*)(abf + (size_t)s * KTOT + KS + sl * 8);
    a0 += bflo(u.x); a1 += bfhi(u.x); a2 += bflo(u.y); a3 += bfhi(u.y);
    a4 += bflo(u.z); a5 += bfhi(u.z); a6 += bflo(u.w); a7 += bfhi(u.w);
  }
  if (j < ne && half == 0) {                     // odd tail: half 0 only
    const int s = sorted_src[o + j];
    const uint4 u = *(const uint4*)(abf + (size_t)s * KTOT + KS + sl * 8);
    a0 += bflo(u.x); a1 += bfhi(u.x); a2 += bflo(u.y); a3 += bfhi(u.y);
    a4 += bflo(u.z); a5 += bfhi(u.z); a6 += bflo(u.w); a7 += bfhi(u.w);
  }
  a0 += __shfl_xor(a0, 32); a1 += __shfl_xor(a1, 32);
  a2 += __shfl_xor(a2, 32); a3 += __shfl_xor(a3, 32);
  a4 += __shfl_xor(a4, 32); a5 += __shfl_xor(a5, 32);
  a6 += __shfl_xor(a6, 32); a7 += __shfl_xor(a7, 32);
  if (half == 0) {
    const int node = seg >> 3, r = seg & 7;
    union { unsigned short u[8]; uint4 q; } pk;
    pk.u[0] = f2bf(a0); pk.u[1] = f2bf(a1); pk.u[2] = f2bf(a2); pk.u[3] = f2bf(a3);
    pk.u[4] = f2bf(a4); pk.u[5] = f2bf(a5); pk.u[6] = f2bf(a6); pk.u[7] = f2bf(a7);
    *(uint4*)(abf + (size_t)node * KTOT + r * IN_DIM + sl * 8) = pk.q;
  }
}

// C[20000][800] = Abf[20000][2304] @ WcatT^T + bias.
// 256x160 tile, BK=64, 8 waves 4Mx2N (64x80 each, acc[4][5]); R6 4-phase
// schedule; triple-buffer 156KB LDS, dist-2, counted vmcnt(7)/K-tile;
// 7 gloads/thread/tile (A:4, B:2.5 -- half-instr idempotently duplicated by
// waves 4-7 so per-wave load count is uniform).  No column padding (800=5x160).
__global__ __launch_bounds__(512) void gemm_kernel(
    const unsigned short* __restrict__ abf,
    const unsigned short* __restrict__ wcatT,
    const float* __restrict__ bias, float* __restrict__ out) {
  __shared__ __align__(16) char lds[3 * LBUF];   // 159744 B

  // T1: bijective XCD-chunk swizzle; col-fastest (A row-panel L2-resident).
  const int lin = blockIdx.x;
  const int q8 = NWG >> 3, r8 = NWG & 7;         // 49, 3
  const int xcd = lin & 7, idx = lin >> 3;
  const int wg = (xcd < r8 ? xcd * (q8 + 1) : r8 * (q8 + 1) + (xcd - r8) * q8) + idx;
  const int row0 = (wg / NT) * BM;
  const int col0 = (wg % NT) * BN;

  const int tid = threadIdx.x;
  const int w = tid >> 6, l = tid & 63;
  const int wm = w >> 1, wn = w & 1;             // wave: rows wm*64+64, cols wn*80+80
  const int la = l & 15, lg = l >> 4;
  const int l3 = l >> 3;
  const int sch = (l & 7) ^ l3;                  // pre-swizzled global k-chunk (T2)

  // A staging: instr i covers rows i*64 + w*8 + l3 (i=0..3)
  const unsigned short* gA[4];
  #pragma unroll
  for (int i = 0; i < 4; ++i) {
    int ga = row0 + i * 64 + w * 8 + l3;
    ga = (ga < N_NODES) ? ga : (N_NODES - 1);    // clamp: garbage rows never stored
    gA[i] = abf + (size_t)ga * KTOT + sch * 8;
  }
  // B staging: instr0 rows 0-63, instr1 rows 64-127, instr2 rows 128-159 by
  // waves 0-3; waves 4-7 idempotently redo instr0's loads (same src, same dest).
  const int b2row = (w < 4) ? (128 + w * 8 + l3) : ((w - 4) * 8 + l3);
  const unsigned short* gB0 = wcatT + (size_t)(col0 + w * 8 + l3) * KTOT + sch * 8;
  const unsigned short* gB1 = wcatT + (size_t)(col0 + 64 + w * 8 + l3) * KTOT + sch * 8;
  const unsigned short* gB2 = wcatT + (size_t)(col0 + b2row) * KTOT + sch * 8;
  const int dB2 = (w < 4) ? (ABYTES + 16384 + w * 1024) : (ABYTES + (w - 4) * 1024);

  f32x4_t acc[4][5];
  #pragma unroll
  for (int i = 0; i < 4; ++i)
    #pragma unroll
    for (int j = 0; j < 5; ++j)
      acc[i][j] = (f32x4_t)(0.0f);

  auto stage_all = [&](int buf, int kt) {
    char* base = lds + buf * LBUF;
    const int ko = kt * BK;
    gload16(gA[0] + ko, base + w * 1024);
    gload16(gA[1] + ko, base + 8192 + w * 1024);
    gload16(gA[2] + ko, base + 16384 + w * 1024);
    gload16(gA[3] + ko, base + 24576 + w * 1024);
    gload16(gB0 + ko, base + ABYTES + w * 1024);
    gload16(gB1 + ko, base + ABYTES + 8192 + w * 1024);
    gload16(gB2 + ko, base + dB2);
  };

  stage_all(0, 0);
  stage_all(1, 1);                               // 14 loads in flight

  for (int kt = 0; kt < NKT; ++kt) {
    const int cbuf = kt % 3;
    const int pbuf = (kt + 2) % 3;
    const bool pf = (kt + 2) < NKT;
    const int pko = (kt + 2) * BK;
    const char* Ab = lds + cbuf * LBUF;
    const char* Bb = Ab + ABYTES;
    char* pbase = lds + pbuf * LBUF;

    // my 7 loads for kt done; kt+1's 7 stay in flight (T4 counted)
    if (kt + 1 < NKT) { asm volatile("s_waitcnt vmcnt(7)" ::: "memory"); }
    else              { asm volatile("s_waitcnt vmcnt(0)" ::: "memory"); }
    __builtin_amdgcn_sched_barrier(0);
    __builtin_amdgcn_s_barrier();                // all waves' staging visible

    short8_t af0, af1, bfv[5];

    // ---- phase 0: s=0, mf 0-1 (reads bfv for s=0) ----
    {
      const int r0 = wm * 64 + la, r1 = wm * 64 + 16 + la;
      af0 = *(const short8_t*)(Ab + r0 * 128 + ((lg << 4) ^ ((r0 & 7) << 4)));
      af1 = *(const short8_t*)(Ab + r1 * 128 + ((lg << 4) ^ ((r1 & 7) << 4)));
      #pragma unroll
      for (int nf = 0; nf < 5; ++nf) {
        const int rr = wn * 80 + nf * 16 + la;
        bfv[nf] = *(const short8_t*)(Bb + rr * 128 + ((lg << 4) ^ ((rr & 7) << 4)));
      }
      if (pf) { gload16(gA[0] + pko, pbase + w * 1024);
                gload16(gA[1] + pko, pbase + 8192 + w * 1024); }
      __builtin_amdgcn_s_barrier();
      asm volatile("s_waitcnt lgkmcnt(0)" ::: "memory");
      __builtin_amdgcn_sched_barrier(0);
      __builtin_amdgcn_s_setprio(1);
      #pragma unroll
      for (int nf = 0; nf < 5; ++nf)
        acc[0][nf] = __builtin_amdgcn_mfma_f32_16x16x32_bf16(af0, bfv[nf], acc[0][nf], 0, 0, 0);
      #pragma unroll
      for (int nf = 0; nf < 5; ++nf)
        acc[1][nf] = __builtin_amdgcn_mfma_f32_16x16x32_bf16(af1, bfv[nf], acc[1][nf], 0, 0, 0);
      __builtin_amdgcn_s_setprio(0);
      __builtin_amdgcn_s_barrier();
    }
    // ---- phase 1: s=0, mf 2-3 (reuse bfv) ----
    {
      const int r0 = wm * 64 + 32 + la, r1 = wm * 64 + 48 + la;
      af0 = *(const short8_t*)(Ab + r0 * 128 + ((lg << 4) ^ ((r0 & 7) << 4)));
      af1 = *(const short8_t*)(Ab + r1 * 128 + ((lg << 4) ^ ((r1 & 7) << 4)));
      if (pf) { gload16(gA[2] + pko, pbase + 16384 + w * 1024);
                gload16(gA[3] + pko, pbase + 24576 + w * 1024); }
      __builtin_amdgcn_s_barrier();
      asm volatile("s_waitcnt lgkmcnt(0)" ::: "memory");
      __builtin_amdgcn_sched_barrier(0);
      __builtin_amdgcn_s_setprio(1);
      #pragma unroll
      for (int nf = 0; nf < 5; ++nf)
        acc[2][nf] = __builtin_amdgcn_mfma_f32_16x16x32_bf16(af0, bfv[nf], acc[2][nf], 0, 0, 0);
      #pragma unroll
      for (int nf = 0; nf < 5; ++nf)
        acc[3][nf] = __builtin_amdgcn_mfma_f32_16x16x32_bf16(af1, bfv[nf], acc[3][nf], 0, 0, 0);
      __builtin_amdgcn_s_setprio(0);
      __builtin_amdgcn_s_barrier();
    }
    // ---- phase 2: s=1, mf 0-1 (reads bfv for s=1) ----
    {
      const int r0 = wm * 64 + la, r1 = wm * 64 + 16 + la;
      af0 = *(const short8_t*)(Ab + r0 * 128 + (((4 + lg) << 4) ^ ((r0 & 7) << 4)));
      af1 = *(const short8_t*)(Ab + r1 * 128 + (((4 + lg) << 4) ^ ((r1 & 7) << 4)));
      #pragma unroll
      for (int nf = 0; nf < 5; ++nf) {
        const int rr = wn * 80 + nf * 16 + la;
        bfv[nf] = *(const short8_t*)(Bb + rr * 128 + (((4 + lg) << 4) ^ ((rr & 7) << 4)));
      }
      if (pf) { gload16(gB0 + pko, pbase + ABYTES + w * 1024);
                gload16(gB1 + pko, pbase + ABYTES + 8192 + w * 1024); }
      __builtin_amdgcn_s_barrier();
      asm volatile("s_waitcnt lgkmcnt(0)" ::: "memory");
      __builtin_amdgcn_sched_barrier(0);
      __builtin_amdgcn_s_setprio(1);
      #pragma unroll
      for (int nf = 0; nf < 5; ++nf)
        acc[0][nf] = __builtin_amdgcn_mfma_f32_16x16x32_bf16(af0, bfv[nf], acc[0][nf], 0, 0, 0);
      #pragma unroll
      for (int nf = 0; nf < 5; ++nf)
        acc[1][nf] = __builtin_amdgcn_mfma_f32_16x16x32_bf16(af1, bfv[nf], acc[1][nf], 0, 0, 0);
      __builtin_amdgcn_s_setprio(0);
      __builtin_amdgcn_s_barrier();
    }
    // ---- phase 3: s=1, mf 2-3 (reuse bfv) ----
    {
      const int r0 = wm * 64 + 32 + la, r1 = wm * 64 + 48 + la;
      af0 = *(const short8_t*)(Ab + r0 * 128 + (((4 + lg) << 4) ^ ((r0 & 7) << 4)));
      af1 = *(const short8_t*)(Ab + r1 * 128 + (((4 + lg) << 4) ^ ((r1 & 7) << 4)));
      if (pf) { gload16(gB2 + pko, pbase + dB2); }
      __builtin_amdgcn_s_barrier();
      asm volatile("s_waitcnt lgkmcnt(0)" ::: "memory");
      __builtin_amdgcn_sched_barrier(0);
      __builtin_amdgcn_s_setprio(1);
      #pragma unroll
      for (int nf = 0; nf < 5; ++nf)
        acc[2][nf] = __builtin_amdgcn_mfma_f32_16x16x32_bf16(af0, bfv[nf], acc[2][nf], 0, 0, 0);
      #pragma unroll
      for (int nf = 0; nf < 5; ++nf)
        acc[3][nf] = __builtin_amdgcn_mfma_f32_16x16x32_bf16(af1, bfv[nf], acc[3][nf], 0, 0, 0);
      __builtin_amdgcn_s_setprio(0);
      __builtin_amdgcn_s_barrier();
    }
  }

  #pragma unroll
  for (int nf = 0; nf < 5; ++nf) {
    const int gcol = col0 + wn * 80 + nf * 16 + la;    // always < 800
    const float bv = bias[gcol];
    #pragma unroll
    for (int f = 0; f < 4; ++f) {
      const int gr0 = row0 + wm * 64 + f * 16 + lg * 4;
      #pragma unroll
      for (int j = 0; j < 4; ++j) {
        const int gr = gr0 + j;
        if (gr < N_NODES)
          out[(size_t)gr * OUT_DIM + gcol] = acc[f][nf][j] + bv;
      }
    }
  }
}

extern "C" void kernel_launch(void* const* d_in, const int* in_sizes, int n_in,
                              void* d_out, int out_size, void* d_ws, size_t ws_size,
                              hipStream_t stream) {
  const float* x     = (const float*)d_in[0];
  const int*   ei    = (const int*)d_in[1];
  const int*   et    = (const int*)d_in[2];
  const float* bases = (const float*)d_in[3];
  const float* att   = (const float*)d_in[4];
  const float* root  = (const float*)d_in[5];
  const float* bias  = (const float*)d_in[6];
  float* out = (float*)d_out;

  char* p = (char*)d_ws;
  unsigned short* abf   = (unsigned short*)p;  p += (size_t)N_NODES * KTOT * 2;  // 92,160,000
  unsigned short* wcatT = (unsigned short*)p;  p += (size_t)NPAD * KTOT * 2;     //  4,718,592
  int* cnt        = (int*)p;                   p += (size_t)NSEG * 4;
  int* off        = (int*)p;                   p += (size_t)NSEG * 4;
  int* cur        = (int*)p;                   p += (size_t)NSEG * 4;
  int* sorted_src = (int*)p;                   p += (size_t)N_EDGES * 4;
  int* bsum       = (int*)p;                   p += 4096;

  init_kernel<<<INIT_NWG, 256, 0, stream>>>(x, bases, att, root, cnt, abf, wcatT);
  hist_kernel<<<N_EDGES / 256, 256, 0, stream>>>(ei, et, cnt);
  scan_reduce_kernel<<<NB, 256, 0, stream>>>(cnt, bsum);
  scan_bsum_kernel<<<1, 1024, 0, stream>>>(bsum);
  scan_final_kernel<<<NB, 256, 0, stream>>>(cnt, bsum, off, cur);
  reorder_kernel<<<N_EDGES / 256, 256, 0, stream>>>(ei, et, cur, sorted_src);
  aggregate_kernel<<<NSEG / 4, 256, 0, stream>>>(cnt, off, sorted_src, abf);
  gemm_kernel<<<NWG, 512, 0, stream>>>(abf, wcatT, bias, out);
}